// Round 7
// baseline (227.781 us; speedup 1.0000x reference)
//
#include <hip/hip_runtime.h>
#include <hip/hip_bf16.h>

// B=4 T=2048 C=1024 H=16 hd=64, causal MHSA, f32 in/out, bf16 MFMA internally.
// Pipeline: cvt(x) / transpose-cvt(w) -> GEMM1 (qkv) -> transpose V -> flash attn -> GEMM2.
// Attn R7: 1024-thr blocks, 16 waves = 8 q-strips x 2 KV-halves (even/odd tiles),
//   paired q-tiles {p,7-p} (uniform 18 iters, 256 blocks = 1/CU, 16 waves/CU),
//   2 tiles staged+computed per barrier, in-LDS f32 flash-merge of KV-half partials.

typedef float f32x4 __attribute__((ext_vector_type(4)));
typedef float f32x16 __attribute__((ext_vector_type(16)));
typedef __bf16 bf16x8 __attribute__((ext_vector_type(8)));
typedef short short8v __attribute__((ext_vector_type(8)));
typedef unsigned int u32x4 __attribute__((ext_vector_type(4)));

__device__ __forceinline__ unsigned short f2bf(float f) {
  __hip_bfloat16 h = __float2bfloat16(f);
  return __builtin_bit_cast(unsigned short, h);
}

__device__ __forceinline__ void glds16(const void* g, void* l) {
  __builtin_amdgcn_global_load_lds((const __attribute__((address_space(1))) void*)g,
                                   (__attribute__((address_space(3))) void*)l, 16, 0, 0);
}

// ---------------- conversions ----------------
__global__ void cvt_f32_bf16_kernel(const float* __restrict__ in,
                                    unsigned short* __restrict__ out, int n) {
  int stride = gridDim.x * blockDim.x * 4;
  for (int i = (blockIdx.x * blockDim.x + threadIdx.x) * 4; i < n; i += stride) {
    float4 v = *(const float4*)(in + i);
    ushort4 o;
    o.x = f2bf(v.x); o.y = f2bf(v.y); o.z = f2bf(v.z); o.w = f2bf(v.w);
    *(ushort4*)(out + i) = o;
  }
}

// in: [K][N] f32 row-major -> out: [N][K] bf16 row-major
__global__ void transpose_cvt_kernel(const float* __restrict__ in,
                                     unsigned short* __restrict__ out, int K, int N) {
  __shared__ unsigned short tile[32][33];
  int tx = threadIdx.x & 31, ty = threadIdx.x >> 5;
  int n0 = blockIdx.x * 32, k0 = blockIdx.y * 32;
#pragma unroll
  for (int i = 0; i < 32; i += 8)
    tile[ty + i][tx] = f2bf(in[(size_t)(k0 + ty + i) * N + n0 + tx]);
  __syncthreads();
#pragma unroll
  for (int i = 0; i < 32; i += 8)
    out[(size_t)(n0 + ty + i) * K + k0 + tx] = tile[tx][ty + i];
}

// ---------------- GEMM: C[m][n] = sum_k A[m][k]*Bt[n][k] + bias[n] ----------------
template <int OUT_F32>
__global__ __launch_bounds__(256) void gemm_bt_kernel(
    const unsigned short* __restrict__ A, const unsigned short* __restrict__ Bt,
    const float* __restrict__ bias, void* __restrict__ Cv, int M, int N, int K) {
  __shared__ unsigned short sA[128 * 32];
  __shared__ unsigned short sB[128 * 32];
  int tid = threadIdx.x;
  int lane = tid & 63, wid = tid >> 6;
  int g = lane >> 4, r16 = lane & 15;
  int m0 = blockIdx.y * 128, n0 = blockIdx.x * 128;
  int wm = wid >> 1, wn = wid & 1;
  f32x4 acc[4][4] = {};
  int srow = tid >> 2, scol = (tid & 3) * 8;
  const unsigned short* Ap0 = A + (size_t)(m0 + srow) * K + scol;
  const unsigned short* Ap1 = A + (size_t)(m0 + 64 + srow) * K + scol;
  const unsigned short* Bp0 = Bt + (size_t)(n0 + srow) * K + scol;
  const unsigned short* Bp1 = Bt + (size_t)(n0 + 64 + srow) * K + scol;
  unsigned short* la0 = sA + tid * 8;
  unsigned short* la1 = sA + 2048 + tid * 8;
  unsigned short* lb0 = sB + tid * 8;
  unsigned short* lb1 = sB + 2048 + tid * 8;
  for (int kt = 0; kt < K; kt += 32) {
    glds16(Ap0 + kt, la0);
    glds16(Ap1 + kt, la1);
    glds16(Bp0 + kt, lb0);
    glds16(Bp1 + kt, lb1);
    __syncthreads();
    bf16x8 af[4], bfr[4];
#pragma unroll
    for (int m = 0; m < 4; ++m)
      af[m] = *(const bf16x8*)&sA[(wm * 64 + m * 16 + r16) * 32 + g * 8];
#pragma unroll
    for (int n = 0; n < 4; ++n)
      bfr[n] = *(const bf16x8*)&sB[(wn * 64 + n * 16 + r16) * 32 + g * 8];
#pragma unroll
    for (int m = 0; m < 4; ++m)
#pragma unroll
      for (int n = 0; n < 4; ++n)
        acc[m][n] = __builtin_amdgcn_mfma_f32_16x16x32_bf16(af[m], bfr[n], acc[m][n], 0, 0, 0);
    __syncthreads();
  }
#pragma unroll
  for (int m = 0; m < 4; ++m)
#pragma unroll
    for (int n = 0; n < 4; ++n)
#pragma unroll
      for (int r = 0; r < 4; ++r) {
        int row = m0 + wm * 64 + m * 16 + g * 4 + r;
        int col = n0 + wn * 64 + n * 16 + r16;
        float v = acc[m][n][r] + bias[col];
        if (OUT_F32)
          ((float*)Cv)[(size_t)row * N + col] = v;
        else
          ((unsigned short*)Cv)[(size_t)row * N + col] = f2bf(v);
      }
}

// ---------------- V transpose: qkv[:, 2048+h*64+d] -> vT[(bh*64+d)][t] ----------------
__global__ void transpose_v_kernel(const unsigned short* __restrict__ qkv,
                                   unsigned short* __restrict__ vT) {
  __shared__ unsigned short tl[64][80];
  int t0 = blockIdx.x * 64;
  int bh = blockIdx.y, b = bh >> 4, h = bh & 15;
  int tid = threadIdx.x;
  int row = tid >> 2, c0 = (tid & 3) * 16;
  const unsigned short* src =
      qkv + (size_t)(b * 2048 + t0 + row) * 3072 + 2048 + h * 64 + c0;
  short8v a0 = *(const short8v*)src;
  short8v a1 = *(const short8v*)(src + 8);
#pragma unroll
  for (int j = 0; j < 8; ++j) tl[c0 + j][row] = (unsigned short)a0[j];
#pragma unroll
  for (int j = 0; j < 8; ++j) tl[c0 + 8 + j][row] = (unsigned short)a1[j];
  __syncthreads();
  int d = tid >> 2, tc = (tid & 3) * 16;
  unsigned short* dst = vT + (size_t)(bh * 64 + d) * 2048 + t0 + tc;
  *(short8v*)dst = *(const short8v*)&tl[d][tc];
  *(short8v*)(dst + 8) = *(const short8v*)&tl[d][tc + 8];
}

// ---------------- flash attention (swapped-QK, KV-split, in-LDS merge) ----------------
// 1024 threads = 16 waves: strip = w&7 (32 q rows), kvh = w>>3 (even/odd kv tiles).
// Per wave: S = mfma_32x32x16(K,Q) (q lane-local), in-reg softmax, reg-P PV.
// Per iteration j: stage tiles 2(j+1),2(j+1)+1; compute tile 2j+kvh; one barrier.
// Phase = one q-tile; block runs phases {pairI, 7-pairI} -> uniform 18 iters.
// Phase end: f32 flash-merge of kvh=1 partials into kvh=0 via LDS (2 rounds).
// Grid 256 = 1 block/CU; XCD packing: id&7 = xcd owns bh in [xcd*8, xcd*8+8).
__global__ __launch_bounds__(1024, 4) void attn_kernel(
    const unsigned short* __restrict__ qkv, const unsigned short* __restrict__ vT,
    unsigned short* __restrict__ ao) {
  // 64KB: K slot (par,half) @ (par*2+h)*4096 shorts; V @ 16384 + same.
  // Merge alias: fO = (float*)sMem [4][64][32]; fM/fL @ +16384 shorts.
  __shared__ unsigned short sMem[32768];
  const int T = 2048, C3 = 3072;
  const float SCL = 0.18033688011112042f;     // 0.125 * log2(e)
  int x = blockIdx.x;                         // 0..255
  int xcd = x & 7, j2 = x >> 3;               // j2 0..31
  int bh = xcd * 8 + (j2 & 7);
  int pairI = j2 >> 3;                        // 0..3
  int b = bh >> 4, h = bh & 15;
  int tid = threadIdx.x, lane = tid & 63, w = tid >> 6;   // w 0..15
  int l31 = lane & 31, hi = lane >> 5;
  int strip = w & 7, kvh = w >> 3;

  // staging: th = tile-of-pair (0/1), tc = 16B chunk within tile
  int th = tid >> 9, tc = tid & 511;
  int srw = tc >> 3, oct = (tc & 7) ^ (srw & 7);
  const unsigned short* Kb = qkv + (size_t)(b * T + srw) * C3 + 1024 + h * 64 + oct * 8;
  const unsigned short* Vb = vT + (size_t)(bh * 64 + srw) * 2048 + oct * 8;

  auto STAGE = [&](int par, int jp) {  // stage pair jp (tiles 2jp+0, 2jp+1) into slot par
    int kv0 = (2 * jp + th) * 64;
    glds16(Kb + (size_t)kv0 * C3, &sMem[(par * 2 + th) * 4096 + tc * 8]);
    glds16(Vb + kv0, &sMem[16384 + (par * 2 + th) * 4096 + tc * 8]);
  };

#pragma unroll 1
  for (int ph = 0; ph < 2; ++ph) {
    int qt = ph ? (7 - pairI) : pairI;
    int wq0 = qt * 256 + strip * 32;  // wave's first q row; lane's q = wq0 + l31

    // Q fragments (B-operand): Q[wq0+l31][d0*16 + hi*8 + j]
    const unsigned short* qp = qkv + (size_t)(b * T + wq0 + l31) * C3 + h * 64;
    bf16x8 qf[4];
#pragma unroll
    for (int d0 = 0; d0 < 4; ++d0)
      qf[d0] = *(const bf16x8*)(qp + d0 * 16 + hi * 8);

    f32x16 o[2] = {};
    float m_r = -3e38f, l_r = 0.f;

    int NJ = 2 * qt + 2;
    STAGE(0, 0);
    __syncthreads();
#pragma unroll 1
    for (int j = 0; j < NJ; ++j) {
      int par = j & 1;
      if (j + 1 < NJ) STAGE(par ^ 1, j + 1);
      int kv0 = (2 * j + kvh) * 64;
      if (kv0 <= wq0 + 31) {  // wave-uniform: tile has any valid (q,kv)
        const unsigned short* Kc = &sMem[(par * 2 + kvh) * 4096];
        const unsigned short* Vc = &sMem[16384 + (par * 2 + kvh) * 4096];
        // ---- S[kv][q] = K Q^T : A=K (row=kv), B=Q (col=q) ----
        f32x16 s[2] = {};
        __builtin_amdgcn_s_setprio(1);
#pragma unroll
        for (int d0 = 0; d0 < 4; ++d0) {
          int oc = ((d0 * 2 + hi) ^ (l31 & 7)) * 8;
          bf16x8 kf0 = *(const bf16x8*)&Kc[l31 * 64 + oc];
          bf16x8 kf1 = *(const bf16x8*)&Kc[(32 + l31) * 64 + oc];
          s[0] = __builtin_amdgcn_mfma_f32_32x32x16_bf16(kf0, qf[d0], s[0], 0, 0, 0);
          s[1] = __builtin_amdgcn_mfma_f32_32x32x16_bf16(kf1, qf[d0], s[1], 0, 0, 0);
        }
        __builtin_amdgcn_s_setprio(0);

        // ---- mask (diag tiles only): valid iff kv_local <= q - kv0 ----
        if (kv0 + 63 > wq0) {
          int thr = wq0 + l31 - kv0 - 4 * hi;
#pragma unroll
          for (int sub = 0; sub < 2; ++sub)
#pragma unroll
            for (int r = 0; r < 16; ++r) {
              int cc = sub * 32 + (r & 3) + 8 * (r >> 2);
              s[sub][r] = (cc <= thr) ? s[sub][r] : -3e38f;
            }
        }

        // ---- row max: pairwise + tree (depth 5) + one cross-half ----
        float tm[16];
#pragma unroll
        for (int r = 0; r < 16; ++r) tm[r] = fmaxf(s[0][r], s[1][r]);
#pragma unroll
        for (int st = 8; st >= 1; st >>= 1)
#pragma unroll
          for (int r = 0; r < 8; ++r)
            if (r < st) tm[r] = fmaxf(tm[r], tm[r + st]);
        float rm = fmaxf(tm[0], __shfl_xor(tm[0], 32, 64));

        // ---- defer-max: rescale only when max grew past threshold ----
        if (!__all(rm <= m_r + 44.0f)) {
          float mn = fmaxf(m_r, rm);
          float alpha = exp2f((m_r - mn) * SCL);
          m_r = mn;
          l_r *= alpha;
#pragma unroll
          for (int r = 0; r < 16; ++r) {
            int qrow = (r & 3) + 8 * (r >> 2) + 4 * hi;
            float a = __shfl(alpha, qrow, 64);
            o[0][r] *= a;
            o[1][r] *= a;
          }
        }

        // ---- P = exp2(S*SCL - m*SCL), row-sum via tree ----
        float ms = m_r * SCL;
#pragma unroll
        for (int sub = 0; sub < 2; ++sub)
#pragma unroll
          for (int r = 0; r < 16; ++r)
            s[sub][r] = exp2f(fmaf(s[sub][r], SCL, -ms));
        float ts[16];
#pragma unroll
        for (int r = 0; r < 16; ++r) ts[r] = s[0][r] + s[1][r];
#pragma unroll
        for (int st = 8; st >= 1; st >>= 1)
#pragma unroll
          for (int r = 0; r < 8; ++r)
            if (r < st) ts[r] += ts[r + st];
        l_r += ts[0] + __shfl_xor(ts[0], 32, 64);

        // ---- pack P to bf16 pairs, half-wave exchange -> A-frags ----
        unsigned int pk[2][8];
#pragma unroll
        for (int sub = 0; sub < 2; ++sub)
#pragma unroll
          for (int i = 0; i < 8; ++i) {
            unsigned int lo = f2bf(s[sub][2 * i]);
            unsigned int hh = f2bf(s[sub][2 * i + 1]);
            pk[sub][i] = lo | (hh << 16);
          }
        unsigned int rc[2][4];
#pragma unroll
        for (int sub = 0; sub < 2; ++sub) {
          unsigned int s0 = hi ? pk[sub][0] : pk[sub][2];
          unsigned int s1 = hi ? pk[sub][1] : pk[sub][3];
          unsigned int s2 = hi ? pk[sub][4] : pk[sub][6];
          unsigned int s3 = hi ? pk[sub][5] : pk[sub][7];
          rc[sub][0] = __shfl_xor(s0, 32, 64);
          rc[sub][1] = __shfl_xor(s1, 32, 64);
          rc[sub][2] = __shfl_xor(s2, 32, 64);
          rc[sub][3] = __shfl_xor(s3, 32, 64);
        }

        // ---- O += P V : A=P (row=q, k=kv16), B=V (col=d) ----
        __builtin_amdgcn_s_setprio(1);
#pragma unroll
        for (int sub = 0; sub < 2; ++sub)
#pragma unroll
          for (int t = 0; t < 2; ++t) {
            u32x4 av;
            av.x = hi ? rc[sub][2 * t]     : pk[sub][4 * t];
            av.y = hi ? rc[sub][2 * t + 1] : pk[sub][4 * t + 1];
            av.z = hi ? pk[sub][4 * t + 2] : rc[sub][2 * t];
            av.w = hi ? pk[sub][4 * t + 3] : rc[sub][2 * t + 1];
            bf16x8 pa = __builtin_bit_cast(bf16x8, av);
            int kvs = sub * 2 + t;
            int ocv = ((kvs * 2 + hi) ^ (l31 & 7)) * 8;
            bf16x8 vf0 = *(const bf16x8*)&Vc[l31 * 64 + ocv];
            bf16x8 vf1 = *(const bf16x8*)&Vc[(32 + l31) * 64 + ocv];
            o[0] = __builtin_amdgcn_mfma_f32_32x32x16_bf16(pa, vf0, o[0], 0, 0, 0);
            o[1] = __builtin_amdgcn_mfma_f32_32x32x16_bf16(pa, vf1, o[1], 0, 0, 0);
          }
        __builtin_amdgcn_s_setprio(0);
      }
      __syncthreads();  // drains vmcnt for staged pair + protects buffer swap
    }

    // ---- merge kvh=1 partials into kvh=0 (f32, 2 strip-rounds over 32KB LDS) ----
    float* fO = (float*)sMem;               // [4][64][32]
    float* fM = (float*)&sMem[16384];       // [256]
    float* fL = fM + 256;                   // [256]
    int mi = (strip & 3) * 64 + lane;
    int mbase = mi * 32;
#pragma unroll 1
    for (int mr = 0; mr < 2; ++mr) {
      if (kvh == 1 && (strip >> 2) == mr) {
#pragma unroll
        for (int g = 0; g < 8; ++g) {
          f32x4 v;
#pragma unroll
          for (int e = 0; e < 4; ++e)
            v[e] = (g < 4) ? o[0][g * 4 + e] : o[1][(g - 4) * 4 + e];
          *(f32x4*)&fO[mbase + ((g ^ (lane & 7)) << 2)] = v;  // swizzled slot
        }
        fM[mi] = m_r;
        fL[mi] = l_r;
      }
      __syncthreads();
      if (kvh == 0 && (strip >> 2) == mr) {
        float O1[32];
#pragma unroll
        for (int g = 0; g < 8; ++g) {
          f32x4 v = *(const f32x4*)&fO[mbase + ((g ^ (lane & 7)) << 2)];
#pragma unroll
          for (int e = 0; e < 4; ++e) O1[g * 4 + e] = v[e];
        }
        float m1 = fM[mi], l1 = fL[mi];
        float mm = fmaxf(m_r, m1);
        float a0 = exp2f((m_r - mm) * SCL);
        float a1 = exp2f((m1 - mm) * SCL);
        l_r = l_r * a0 + l1 * a1;
#pragma unroll
        for (int r = 0; r < 16; ++r) {
          int qrow = (r & 3) + 8 * (r >> 2) + 4 * hi;
          float a0r = __shfl(a0, qrow, 64);
          float a1r = __shfl(a1, qrow, 64);
          o[0][r] = o[0][r] * a0r + O1[r] * a1r;
          o[1][r] = o[1][r] * a0r + O1[16 + r] * a1r;
        }
      }
      __syncthreads();
    }

    // ---- normalize + store (kvh==0 waves own the output) ----
    if (kvh == 0) {
      float inv = 1.f / l_r;
#pragma unroll
      for (int r = 0; r < 16; ++r) {
        int qrow = (r & 3) + 8 * (r >> 2) + 4 * hi;
        float iv = __shfl(inv, qrow, 64);
        size_t base = (size_t)(b * T + wq0 + qrow) * 1024 + h * 64 + l31;
        ao[base] = f2bf(o[0][r] * iv);
        ao[base + 32] = f2bf(o[1][r] * iv);
      }
    }
  }
}

// ---------------- launch ----------------
extern "C" void kernel_launch(void* const* d_in, const int* in_sizes, int n_in,
                              void* d_out, int out_size, void* d_ws, size_t ws_size,
                              hipStream_t stream) {
  const float* x      = (const float*)d_in[0];
  const float* w_qkv  = (const float*)d_in[1];
  const float* b_qkv  = (const float*)d_in[2];
  const float* w_proj = (const float*)d_in[3];
  const float* b_proj = (const float*)d_in[4];
  float* out = (float*)d_out;

  char* ws = (char*)d_ws;
  unsigned short* xb     = (unsigned short*)(ws);
  unsigned short* ao     = (unsigned short*)(ws);             // alias: xb dead after GEMM1
  unsigned short* wqkvT  = (unsigned short*)(ws + (16u << 20));
  unsigned short* wprojT = (unsigned short*)(ws + (22u << 20));
  unsigned short* qkv    = (unsigned short*)(ws + (24u << 20));
  unsigned short* vT     = (unsigned short*)(ws + (72u << 20));

  cvt_f32_bf16_kernel<<<2048, 256, 0, stream>>>(x, xb, 8192 * 1024);
  transpose_cvt_kernel<<<dim3(3072 / 32, 1024 / 32), 256, 0, stream>>>(w_qkv, wqkvT, 1024, 3072);
  transpose_cvt_kernel<<<dim3(1024 / 32, 1024 / 32), 256, 0, stream>>>(w_proj, wprojT, 1024, 1024);

  gemm_bt_kernel<0><<<dim3(3072 / 128, 8192 / 128), 256, 0, stream>>>(
      xb, wqkvT, b_qkv, (void*)qkv, 8192, 3072, 1024);

  transpose_v_kernel<<<dim3(32, 64), 256, 0, stream>>>(qkv, vT);

  attn_kernel<<<dim3(256), 1024, 0, stream>>>(qkv, vT, ao);

  gemm_bt_kernel<1><<<dim3(1024 / 128, 8192 / 128), 256, 0, stream>>>(
      ao, wprojT, b_proj, (void*)out, 8192, 1024, 1024);
}

// Round 8
// 214.163 us; speedup vs baseline: 1.0636x; 1.0636x over previous
//
#include <hip/hip_runtime.h>
#include <hip/hip_bf16.h>

// B=4 T=2048 C=1024 H=16 hd=64, causal MHSA, f32 in/out, bf16 MFMA internally.
// Pipeline: cvt(x) / transpose-cvt(w) -> GEMM1 (qkv) -> transpose V -> flash attn -> GEMM2.
// Attn: swapped-QK (mfma(K,Q), q lane-local), in-register softmax + P, 32x32x16 MFMA.
// R8: R6 structure (512 thr / 8 waves / QBLK=256 / grid 512 / XCD bh-packing) but
//     KV iterated in steps of 128: stage a PAIR of 64-tiles per barrier (dbuf 64KB LDS),
//     compute both sequentially -> barrier count halved (4qt+4 -> 2qt+2 iterations).

typedef float f32x4 __attribute__((ext_vector_type(4)));
typedef float f32x16 __attribute__((ext_vector_type(16)));
typedef __bf16 bf16x8 __attribute__((ext_vector_type(8)));
typedef short short8v __attribute__((ext_vector_type(8)));
typedef unsigned int u32x4 __attribute__((ext_vector_type(4)));

__device__ __forceinline__ unsigned short f2bf(float f) {
  __hip_bfloat16 h = __float2bfloat16(f);
  return __builtin_bit_cast(unsigned short, h);
}

__device__ __forceinline__ void glds16(const void* g, void* l) {
  __builtin_amdgcn_global_load_lds((const __attribute__((address_space(1))) void*)g,
                                   (__attribute__((address_space(3))) void*)l, 16, 0, 0);
}

// ---------------- conversions ----------------
__global__ void cvt_f32_bf16_kernel(const float* __restrict__ in,
                                    unsigned short* __restrict__ out, int n) {
  int stride = gridDim.x * blockDim.x * 4;
  for (int i = (blockIdx.x * blockDim.x + threadIdx.x) * 4; i < n; i += stride) {
    float4 v = *(const float4*)(in + i);
    ushort4 o;
    o.x = f2bf(v.x); o.y = f2bf(v.y); o.z = f2bf(v.z); o.w = f2bf(v.w);
    *(ushort4*)(out + i) = o;
  }
}

// in: [K][N] f32 row-major -> out: [N][K] bf16 row-major
__global__ void transpose_cvt_kernel(const float* __restrict__ in,
                                     unsigned short* __restrict__ out, int K, int N) {
  __shared__ unsigned short tile[32][33];
  int tx = threadIdx.x & 31, ty = threadIdx.x >> 5;
  int n0 = blockIdx.x * 32, k0 = blockIdx.y * 32;
#pragma unroll
  for (int i = 0; i < 32; i += 8)
    tile[ty + i][tx] = f2bf(in[(size_t)(k0 + ty + i) * N + n0 + tx]);
  __syncthreads();
#pragma unroll
  for (int i = 0; i < 32; i += 8)
    out[(size_t)(n0 + ty + i) * K + k0 + tx] = tile[tx][ty + i];
}

// ---------------- GEMM: C[m][n] = sum_k A[m][k]*Bt[n][k] + bias[n] ----------------
template <int OUT_F32>
__global__ __launch_bounds__(256) void gemm_bt_kernel(
    const unsigned short* __restrict__ A, const unsigned short* __restrict__ Bt,
    const float* __restrict__ bias, void* __restrict__ Cv, int M, int N, int K) {
  __shared__ unsigned short sA[128 * 32];
  __shared__ unsigned short sB[128 * 32];
  int tid = threadIdx.x;
  int lane = tid & 63, wid = tid >> 6;
  int g = lane >> 4, r16 = lane & 15;
  int m0 = blockIdx.y * 128, n0 = blockIdx.x * 128;
  int wm = wid >> 1, wn = wid & 1;
  f32x4 acc[4][4] = {};
  int srow = tid >> 2, scol = (tid & 3) * 8;
  const unsigned short* Ap0 = A + (size_t)(m0 + srow) * K + scol;
  const unsigned short* Ap1 = A + (size_t)(m0 + 64 + srow) * K + scol;
  const unsigned short* Bp0 = Bt + (size_t)(n0 + srow) * K + scol;
  const unsigned short* Bp1 = Bt + (size_t)(n0 + 64 + srow) * K + scol;
  unsigned short* la0 = sA + tid * 8;
  unsigned short* la1 = sA + 2048 + tid * 8;
  unsigned short* lb0 = sB + tid * 8;
  unsigned short* lb1 = sB + 2048 + tid * 8;
  for (int kt = 0; kt < K; kt += 32) {
    glds16(Ap0 + kt, la0);
    glds16(Ap1 + kt, la1);
    glds16(Bp0 + kt, lb0);
    glds16(Bp1 + kt, lb1);
    __syncthreads();
    bf16x8 af[4], bfr[4];
#pragma unroll
    for (int m = 0; m < 4; ++m)
      af[m] = *(const bf16x8*)&sA[(wm * 64 + m * 16 + r16) * 32 + g * 8];
#pragma unroll
    for (int n = 0; n < 4; ++n)
      bfr[n] = *(const bf16x8*)&sB[(wn * 64 + n * 16 + r16) * 32 + g * 8];
#pragma unroll
    for (int m = 0; m < 4; ++m)
#pragma unroll
      for (int n = 0; n < 4; ++n)
        acc[m][n] = __builtin_amdgcn_mfma_f32_16x16x32_bf16(af[m], bfr[n], acc[m][n], 0, 0, 0);
    __syncthreads();
  }
#pragma unroll
  for (int m = 0; m < 4; ++m)
#pragma unroll
    for (int n = 0; n < 4; ++n)
#pragma unroll
      for (int r = 0; r < 4; ++r) {
        int row = m0 + wm * 64 + m * 16 + g * 4 + r;
        int col = n0 + wn * 64 + n * 16 + r16;
        float v = acc[m][n][r] + bias[col];
        if (OUT_F32)
          ((float*)Cv)[(size_t)row * N + col] = v;
        else
          ((unsigned short*)Cv)[(size_t)row * N + col] = f2bf(v);
      }
}

// ---------------- V transpose: qkv[:, 2048+h*64+d] -> vT[(bh*64+d)][t] ----------------
__global__ void transpose_v_kernel(const unsigned short* __restrict__ qkv,
                                   unsigned short* __restrict__ vT) {
  __shared__ unsigned short tl[64][80];
  int t0 = blockIdx.x * 64;
  int bh = blockIdx.y, b = bh >> 4, h = bh & 15;
  int tid = threadIdx.x;
  int row = tid >> 2, c0 = (tid & 3) * 16;
  const unsigned short* src =
      qkv + (size_t)(b * 2048 + t0 + row) * 3072 + 2048 + h * 64 + c0;
  short8v a0 = *(const short8v*)src;
  short8v a1 = *(const short8v*)(src + 8);
#pragma unroll
  for (int j = 0; j < 8; ++j) tl[c0 + j][row] = (unsigned short)a0[j];
#pragma unroll
  for (int j = 0; j < 8; ++j) tl[c0 + 8 + j][row] = (unsigned short)a1[j];
  __syncthreads();
  int d = tid >> 2, tc = (tid & 3) * 16;
  unsigned short* dst = vT + (size_t)(bh * 64 + d) * 2048 + t0 + tc;
  *(short8v*)dst = *(const short8v*)&tl[d][tc];
  *(short8v*)(dst + 8) = *(const short8v*)&tl[d][tc + 8];
}

// ---------------- flash attention (swapped-QK, 128-kv per barrier) ----------------
// 512 threads = 8 waves; QBLK=256 (32 q/wave, q = lane&31 lane-local).
// Iteration = 2 KV-tiles of 64 (128 kv): stage pair into dbuf, compute both per wave.
// One q-tile per block; grid 512 = 2 blocks/CU (16 waves/CU); longest-first.
// XCD packing: id&7 = xcd handles bh in [xcd*8, xcd*8+8) -> 4MB K/V per XCD L2.
__global__ __launch_bounds__(512, 4) void attn_kernel(
    const unsigned short* __restrict__ qkv, const unsigned short* __restrict__ vT,
    unsigned short* __restrict__ ao) {
  __shared__ unsigned short sK[2][2][4096];   // [buf][tile][64x64] K  (32KB)
  __shared__ unsigned short sV[2][2][4096];   // [buf][tile][64x64] V^T (32KB)
  const int T = 2048, C3 = 3072;
  const float SCL = 0.18033688011112042f;     // 0.125 * log2(e)
  int x = blockIdx.x;                         // 0..511
  int xcd = x & 7, rest = x >> 3;             // rest 0..63
  int bh = xcd * 8 + (rest & 7);
  int qt = 7 - (rest >> 3);                   // longest-first (qt=7 dispatched first)
  int b = bh >> 4, h = bh & 15;
  int tid = threadIdx.x, lane = tid & 63, w = tid >> 6;  // w 0..7
  int l31 = lane & 31, hi = lane >> 5;

  // staging geometry: 4 chunks of 16B per thread per iteration (2 K-tiles + 2 V-tiles)
  int srw = tid >> 3, oct = (tid & 7) ^ (srw & 7);
  const unsigned short* Kb = qkv + (size_t)(b * T + srw) * C3 + 1024 + h * 64 + oct * 8;
  const unsigned short* Vb = vT + (size_t)(bh * 64 + srw) * 2048 + oct * 8;

  auto STAGE = [&](int buf, int j) {  // stage tiles 2j, 2j+1
    size_t koff = (size_t)(j * 128) * C3;
    glds16(Kb + koff, &sK[buf][0][tid * 8]);
    glds16(Kb + koff + (size_t)64 * C3, &sK[buf][1][tid * 8]);
    glds16(Vb + j * 128, &sV[buf][0][tid * 8]);
    glds16(Vb + j * 128 + 64, &sV[buf][1][tid * 8]);
  };

  int wq0 = qt * 256 + w * 32;  // wave's first q row; lane's q = wq0 + l31

  // Q fragments (B-operand): Q[wq0+l31][d0*16 + hi*8 + j]
  const unsigned short* qp = qkv + (size_t)(b * T + wq0 + l31) * C3 + h * 64;
  bf16x8 qf[4];
#pragma unroll
  for (int d0 = 0; d0 < 4; ++d0)
    qf[d0] = *(const bf16x8*)(qp + d0 * 16 + hi * 8);

  f32x16 o[2] = {};
  float m_r = -3e38f, l_r = 0.f;

  int nj = 2 * qt + 2;  // iterations of 128 kv (tiles 0..4qt+3)
  STAGE(0, 0);
  __syncthreads();
  int cur = 0;
#pragma unroll 1
  for (int j = 0; j < nj; ++j) {
    if (j + 1 < nj) STAGE(cur ^ 1, j + 1);
#pragma unroll
    for (int u = 0; u < 2; ++u) {
      int kv0 = (2 * j + u) * 64;
      if (kv0 <= wq0 + 31) {  // wave-uniform: tile has any valid (q,kv)
        const unsigned short* Kc = &sK[cur][u][0];
        const unsigned short* Vc = &sV[cur][u][0];
        // ---- S[kv][q] = K Q^T : A=K (row=kv), B=Q (col=q) ----
        f32x16 s[2] = {};
        __builtin_amdgcn_s_setprio(1);
#pragma unroll
        for (int d0 = 0; d0 < 4; ++d0) {
          int oc = ((d0 * 2 + hi) ^ (l31 & 7)) * 8;
          bf16x8 kf0 = *(const bf16x8*)&Kc[l31 * 64 + oc];
          bf16x8 kf1 = *(const bf16x8*)&Kc[(32 + l31) * 64 + oc];
          s[0] = __builtin_amdgcn_mfma_f32_32x32x16_bf16(kf0, qf[d0], s[0], 0, 0, 0);
          s[1] = __builtin_amdgcn_mfma_f32_32x32x16_bf16(kf1, qf[d0], s[1], 0, 0, 0);
        }
        __builtin_amdgcn_s_setprio(0);

        // ---- mask (diag tiles only): valid iff kv_local <= q - kv0 ----
        if (kv0 + 63 > wq0) {
          int thr = wq0 + l31 - kv0 - 4 * hi;
#pragma unroll
          for (int sub = 0; sub < 2; ++sub)
#pragma unroll
            for (int r = 0; r < 16; ++r) {
              int cc = sub * 32 + (r & 3) + 8 * (r >> 2);
              s[sub][r] = (cc <= thr) ? s[sub][r] : -3e38f;
            }
        }

        // ---- row max: pairwise + tree (depth 5) + one cross-half ----
        float tm[16];
#pragma unroll
        for (int r = 0; r < 16; ++r) tm[r] = fmaxf(s[0][r], s[1][r]);
#pragma unroll
        for (int st = 8; st >= 1; st >>= 1)
#pragma unroll
          for (int r = 0; r < 8; ++r)
            if (r < st) tm[r] = fmaxf(tm[r], tm[r + st]);
        float rm = fmaxf(tm[0], __shfl_xor(tm[0], 32, 64));

        // ---- defer-max: rescale only when max grew past threshold ----
        if (!__all(rm <= m_r + 44.0f)) {
          float mn = fmaxf(m_r, rm);
          float alpha = exp2f((m_r - mn) * SCL);
          m_r = mn;
          l_r *= alpha;
#pragma unroll
          for (int r = 0; r < 16; ++r) {
            int qrow = (r & 3) + 8 * (r >> 2) + 4 * hi;
            float a = __shfl(alpha, qrow, 64);
            o[0][r] *= a;
            o[1][r] *= a;
          }
        }

        // ---- P = exp2(S*SCL - m*SCL), row-sum via tree ----
        float ms = m_r * SCL;
#pragma unroll
        for (int sub = 0; sub < 2; ++sub)
#pragma unroll
          for (int r = 0; r < 16; ++r)
            s[sub][r] = exp2f(fmaf(s[sub][r], SCL, -ms));
        float ts[16];
#pragma unroll
        for (int r = 0; r < 16; ++r) ts[r] = s[0][r] + s[1][r];
#pragma unroll
        for (int st = 8; st >= 1; st >>= 1)
#pragma unroll
          for (int r = 0; r < 8; ++r)
            if (r < st) ts[r] += ts[r + st];
        l_r += ts[0] + __shfl_xor(ts[0], 32, 64);

        // ---- pack P to bf16 pairs, half-wave exchange -> A-frags ----
        unsigned int pk[2][8];
#pragma unroll
        for (int sub = 0; sub < 2; ++sub)
#pragma unroll
          for (int i = 0; i < 8; ++i) {
            unsigned int lo = f2bf(s[sub][2 * i]);
            unsigned int hh = f2bf(s[sub][2 * i + 1]);
            pk[sub][i] = lo | (hh << 16);
          }
        unsigned int rc[2][4];
#pragma unroll
        for (int sub = 0; sub < 2; ++sub) {
          unsigned int s0 = hi ? pk[sub][0] : pk[sub][2];
          unsigned int s1 = hi ? pk[sub][1] : pk[sub][3];
          unsigned int s2 = hi ? pk[sub][4] : pk[sub][6];
          unsigned int s3 = hi ? pk[sub][5] : pk[sub][7];
          rc[sub][0] = __shfl_xor(s0, 32, 64);
          rc[sub][1] = __shfl_xor(s1, 32, 64);
          rc[sub][2] = __shfl_xor(s2, 32, 64);
          rc[sub][3] = __shfl_xor(s3, 32, 64);
        }

        // ---- O += P V : A=P (row=q, k=kv16), B=V (col=d) ----
        __builtin_amdgcn_s_setprio(1);
#pragma unroll
        for (int sub = 0; sub < 2; ++sub)
#pragma unroll
          for (int t = 0; t < 2; ++t) {
            u32x4 av;
            av.x = hi ? rc[sub][2 * t]     : pk[sub][4 * t];
            av.y = hi ? rc[sub][2 * t + 1] : pk[sub][4 * t + 1];
            av.z = hi ? pk[sub][4 * t + 2] : rc[sub][2 * t];
            av.w = hi ? pk[sub][4 * t + 3] : rc[sub][2 * t + 1];
            bf16x8 pa = __builtin_bit_cast(bf16x8, av);
            int kvs = sub * 2 + t;
            int ocv = ((kvs * 2 + hi) ^ (l31 & 7)) * 8;
            bf16x8 vf0 = *(const bf16x8*)&Vc[l31 * 64 + ocv];
            bf16x8 vf1 = *(const bf16x8*)&Vc[(32 + l31) * 64 + ocv];
            o[0] = __builtin_amdgcn_mfma_f32_32x32x16_bf16(pa, vf0, o[0], 0, 0, 0);
            o[1] = __builtin_amdgcn_mfma_f32_32x32x16_bf16(pa, vf1, o[1], 0, 0, 0);
          }
        __builtin_amdgcn_s_setprio(0);
      }
    }
    __syncthreads();  // drains vmcnt for staged pair + protects buffer swap
    cur ^= 1;
  }

  // ---- normalize + store: O row = (r&3)+8*(r>>2)+4*hi, col d = dt*32+l31 ----
  float inv = 1.f / l_r;
#pragma unroll
  for (int r = 0; r < 16; ++r) {
    int qrow = (r & 3) + 8 * (r >> 2) + 4 * hi;
    float iv = __shfl(inv, qrow, 64);
    size_t base = (size_t)(b * T + wq0 + qrow) * 1024 + h * 64 + l31;
    ao[base] = f2bf(o[0][r] * iv);
    ao[base + 32] = f2bf(o[1][r] * iv);
  }
}

// ---------------- launch ----------------
extern "C" void kernel_launch(void* const* d_in, const int* in_sizes, int n_in,
                              void* d_out, int out_size, void* d_ws, size_t ws_size,
                              hipStream_t stream) {
  const float* x      = (const float*)d_in[0];
  const float* w_qkv  = (const float*)d_in[1];
  const float* b_qkv  = (const float*)d_in[2];
  const float* w_proj = (const float*)d_in[3];
  const float* b_proj = (const float*)d_in[4];
  float* out = (float*)d_out;

  char* ws = (char*)d_ws;
  unsigned short* xb     = (unsigned short*)(ws);
  unsigned short* ao     = (unsigned short*)(ws);             // alias: xb dead after GEMM1
  unsigned short* wqkvT  = (unsigned short*)(ws + (16u << 20));
  unsigned short* wprojT = (unsigned short*)(ws + (22u << 20));
  unsigned short* qkv    = (unsigned short*)(ws + (24u << 20));
  unsigned short* vT     = (unsigned short*)(ws + (72u << 20));

  cvt_f32_bf16_kernel<<<2048, 256, 0, stream>>>(x, xb, 8192 * 1024);
  transpose_cvt_kernel<<<dim3(3072 / 32, 1024 / 32), 256, 0, stream>>>(w_qkv, wqkvT, 1024, 3072);
  transpose_cvt_kernel<<<dim3(1024 / 32, 1024 / 32), 256, 0, stream>>>(w_proj, wprojT, 1024, 1024);

  gemm_bt_kernel<0><<<dim3(3072 / 128, 8192 / 128), 256, 0, stream>>>(
      xb, wqkvT, b_qkv, (void*)qkv, 8192, 3072, 1024);

  transpose_v_kernel<<<dim3(32, 64), 256, 0, stream>>>(qkv, vT);

  attn_kernel<<<dim3(512), 512, 0, stream>>>(qkv, vT, ao);

  gemm_bt_kernel<1><<<dim3(1024 / 128, 8192 / 128), 256, 0, stream>>>(
      ao, wprojT, b_proj, (void*)out, 8192, 1024, 1024);
}